// Round 2
// baseline (243.428 us; speedup 1.0000x reference)
//
#include <hip/hip_runtime.h>

// Dense image warp (bilinear), B=8 H=256 W=256 C=64, fp32.
// One thread = TWO float4s (channel quads q and q+8) of one output pixel.
// 8 threads per pixel.
//
// Block swizzle: batch = blockIdx & 7. Hardware dispatch round-robins
// blockIdx%8 across the 8 XCDs, so each XCD owns exactly one batch:
// - zero cross-XCD duplicate fetch of image lines (per-XCD L2s are private)
// - each XCD streams one contiguous 17 MB image slab row-major
// Flow loads are nontemporal (pure stream; keep L2 for image reuse).
// Output stores are nontemporal (write-once stream).

typedef float f4 __attribute__((ext_vector_type(4)));
typedef float f2 __attribute__((ext_vector_type(2)));

__global__ __launch_bounds__(256) void warp_bilinear_kernel(
    const float* __restrict__ image,
    const float* __restrict__ flow,
    float* __restrict__ out)
{
    constexpr int H = 256, W = 256, C = 64;
    constexpr int QUADS = C / 4;       // 16 float4 per pixel
    constexpr int R = W * QUADS;       // float4s per image row = 4096
    constexpr int PIX_PER_BATCH = H * W;  // 65536

    const int blk = blockIdx.x;
    const int b = blk & 7;             // batch -> XCD (dispatch round-robin)
    const int chunk = blk >> 3;        // [0, 2048) row-major within batch

    const int t = (chunk << 8) + threadIdx.x;  // thread within batch
    const int pp = t >> 3;             // pixel within batch [0, 65536)
    const int q = t & 7;               // handles quads q and q+8

    const int x = pp & (W - 1);
    const int y = pp >> 8;
    const int p = b * PIX_PER_BATCH + pp;   // global pixel index

    // query point = grid - flow (one nontemporal dwordx2)
    const f2 fl = __builtin_nontemporal_load((const f2*)flow + p);
    const float qy = (float)y - fl.x;
    const float qx = (float)x - fl.y;

    // floor clamped to [0, size-2]; alpha clipped to [0,1] (tfa semantics)
    const float fy = fminf(fmaxf(floorf(qy), 0.0f), (float)(H - 2));
    const float fx = fminf(fmaxf(floorf(qx), 0.0f), (float)(W - 2));
    const float ay = fminf(fmaxf(qy - fy, 0.0f), 1.0f);
    const float ax = fminf(fmaxf(qx - fx, 0.0f), 1.0f);
    const int iy = (int)fy;
    const int ix = (int)fx;

    const f4* __restrict__ img4 = (const f4*)image;
    // float4-unit index of (b, iy, ix, 4q); all-32-bit arithmetic
    const int base = ((b * H + iy) * W + ix) * QUADS + q;

    const f4 tl0 = img4[base];
    const f4 tr0 = img4[base + QUADS];
    const f4 bl0 = img4[base + R];
    const f4 br0 = img4[base + R + QUADS];
    const f4 tl1 = img4[base + 8];
    const f4 tr1 = img4[base + QUADS + 8];
    const f4 bl1 = img4[base + R + 8];
    const f4 br1 = img4[base + R + QUADS + 8];

    f4 r0, r1;
    #pragma unroll
    for (int e = 0; e < 4; ++e) {
        float top, bot;
        top = fmaf(ax, tr0[e] - tl0[e], tl0[e]);
        bot = fmaf(ax, br0[e] - bl0[e], bl0[e]);
        r0[e] = fmaf(ay, bot - top, top);
        top = fmaf(ax, tr1[e] - tl1[e], tl1[e]);
        bot = fmaf(ax, br1[e] - bl1[e], bl1[e]);
        r1[e] = fmaf(ay, bot - top, top);
    }

    f4* o4 = (f4*)out;
    const int oidx = (p << 4) + q;     // p * QUADS + q
    __builtin_nontemporal_store(r0, o4 + oidx);
    __builtin_nontemporal_store(r1, o4 + oidx + 8);
}

extern "C" void kernel_launch(void* const* d_in, const int* in_sizes, int n_in,
                              void* d_out, int out_size, void* d_ws, size_t ws_size,
                              hipStream_t stream) {
    const float* image = (const float*)d_in[0];
    const float* flow  = (const float*)d_in[1];
    float* out = (float*)d_out;

    constexpr int B = 8, H = 256, W = 256;
    const int total_threads = B * H * W * 8;   // 4,194,304 (8 threads/pixel)
    const int block = 256;
    const int grid = total_threads / block;    // 16,384

    warp_bilinear_kernel<<<grid, block, 0, stream>>>(image, flow, out);
}

// Round 3
// 237.884 us; speedup vs baseline: 1.0233x; 1.0233x over previous
//
#include <hip/hip_runtime.h>

// Dense image warp (bilinear), B=8 H=256 W=256 C=64, fp32.
// One thread = TWO float4s (channel quads q and q+8) of one output pixel,
// iterated over 8 pixel-groups (one batch per iteration) via grid-stride.
//
// Persistent launch: 2048 blocks x 256 threads = 8 blocks/CU on 256 CUs,
// fully resident, no re-dispatch. Per iteration the NEXT iteration's flow
// value is prefetched before the current gathers are consumed, so the
// flow round-trip hides under the gather round-trip (the kernel is
// latency-bound: measured 2.3 TB/s, VALUBusy 7%, no pipe saturated).
// Linear block->pixel mapping (the R2 batch-per-XCD swizzle regressed).

typedef float f4 __attribute__((ext_vector_type(4)));
typedef float f2 __attribute__((ext_vector_type(2)));

__global__ __launch_bounds__(256) void warp_bilinear_kernel(
    const float* __restrict__ image,
    const float* __restrict__ flow,
    float* __restrict__ out)
{
    constexpr int H = 256, W = 256, C = 64;
    constexpr int QUADS = C / 4;        // 16 float4 per pixel
    constexpr int R = W * QUADS;        // float4s per image row = 4096
    constexpr int STRIDE = 2048 * 256;  // launched threads
    constexpr int ITER = 8;             // 4,194,304 / STRIDE

    const f4* __restrict__ img4 = (const f4*)image;
    const f2* __restrict__ flow2 = (const f2*)flow;
    f4* __restrict__ o4 = (f4*)out;

    int u = blockIdx.x * blockDim.x + threadIdx.x;  // unit = pixel*8 + q
    f2 fl = __builtin_nontemporal_load(flow2 + (u >> 3));

    #pragma unroll 2
    for (int i = 0; i < ITER; ++i) {
        // ---- prefetch next iteration's flow (hides under this gather) ----
        const int un = u + STRIDE;
        f2 fl_next;
        if (i < ITER - 1)
            fl_next = __builtin_nontemporal_load(flow2 + (un >> 3));

        // ---- current unit ----
        const int p = u >> 3;           // pixel index: b*H*W + y*W + x
        const int q = u & 7;            // handles quads q and q+8
        const int x = p & (W - 1);
        const int y = (p >> 8) & (H - 1);

        const float qy = (float)y - fl.x;
        const float qx = (float)x - fl.y;

        // floor clamped to [0, size-2]; alpha clipped to [0,1] (tfa)
        const float fy = fminf(fmaxf(floorf(qy), 0.0f), (float)(H - 2));
        const float fx = fminf(fmaxf(floorf(qx), 0.0f), (float)(W - 2));
        const float ay = fminf(fmaxf(qy - fy, 0.0f), 1.0f);
        const float ax = fminf(fmaxf(qx - fx, 0.0f), 1.0f);
        const int iy = (int)fy;
        const int ix = (int)fx;

        // float4-unit index of (b, iy, ix, 4q); (p & ~0xFFFF) == b*H*W
        const int base = ((p & ~0xFFFF) + (iy << 8) + ix) * QUADS + q;

        const f4 tl0 = img4[base];
        const f4 tr0 = img4[base + QUADS];
        const f4 bl0 = img4[base + R];
        const f4 br0 = img4[base + R + QUADS];
        const f4 tl1 = img4[base + 8];
        const f4 tr1 = img4[base + QUADS + 8];
        const f4 bl1 = img4[base + R + 8];
        const f4 br1 = img4[base + R + QUADS + 8];

        f4 r0, r1;
        #pragma unroll
        for (int e = 0; e < 4; ++e) {
            float top, bot;
            top = fmaf(ax, tr0[e] - tl0[e], tl0[e]);
            bot = fmaf(ax, br0[e] - bl0[e], bl0[e]);
            r0[e] = fmaf(ay, bot - top, top);
            top = fmaf(ax, tr1[e] - tl1[e], tl1[e]);
            bot = fmaf(ax, br1[e] - bl1[e], bl1[e]);
            r1[e] = fmaf(ay, bot - top, top);
        }

        const int oidx = (p << 4) + q;  // p * QUADS + q
        __builtin_nontemporal_store(r0, o4 + oidx);
        __builtin_nontemporal_store(r1, o4 + oidx + 8);

        u = un;
        fl = fl_next;
    }
}

extern "C" void kernel_launch(void* const* d_in, const int* in_sizes, int n_in,
                              void* d_out, int out_size, void* d_ws, size_t ws_size,
                              hipStream_t stream) {
    const float* image = (const float*)d_in[0];
    const float* flow  = (const float*)d_in[1];
    float* out = (float*)d_out;

    const int block = 256;
    const int grid = 2048;   // 8 blocks/CU x 256 CUs, fully resident

    warp_bilinear_kernel<<<grid, block, 0, stream>>>(image, flow, out);
}

// Round 4
// 229.907 us; speedup vs baseline: 1.0588x; 1.0347x over previous
//
#include <hip/hip_runtime.h>

// Dense image warp (bilinear), B=8 H=256 W=256 C=64, fp32.
// REVERT to the round-0 structure, which measured fastest (~63.5 us kernel):
//   - 16 threads per pixel, one thread = one float4 (4 channels)
//   - one-shot launch (32768 blocks), linear block->pixel mapping
//   - plain cached loads and stores (no nontemporal)
// Evidence: R1 (8 thr/px + nt stores) +7 us, R2 (XCD swizzle) +24 us,
// R3 (persistent + prefetch) +14 us. Kernel is gather-latency bound
// (R2 counters: HBM 29%, VALU 7%, nothing saturated); many short waves
// with 4 outstanding gathers each maximize CU-level miss concurrency.
// Only safe micro-cleanups kept: 32-bit index math, float2 flow load.

typedef float f4 __attribute__((ext_vector_type(4)));

__global__ __launch_bounds__(256) void warp_bilinear_kernel(
    const float* __restrict__ image,
    const float* __restrict__ flow,
    float* __restrict__ out)
{
    constexpr int H = 256, W = 256, C = 64;
    constexpr int QUADS = C / 4;   // 16 float4 per pixel
    constexpr int R = W * QUADS;   // float4s per image row = 4096

    const int gid = blockIdx.x * blockDim.x + threadIdx.x;
    const int p = gid >> 4;        // pixel index: b*H*W + y*W + x
    const int q = gid & 15;        // channel quad within pixel

    const int x = p & (W - 1);
    const int y = (p >> 8) & (H - 1);

    // query point = grid - flow (one dwordx2, same address for 16 lanes)
    const float2 fl = ((const float2*)flow)[p];
    const float qy = (float)y - fl.x;
    const float qx = (float)x - fl.y;

    // floor clamped to [0, size-2]; alpha clipped to [0,1] (tfa semantics)
    const float fy = fminf(fmaxf(floorf(qy), 0.0f), (float)(H - 2));
    const float fx = fminf(fmaxf(floorf(qx), 0.0f), (float)(W - 2));
    const float ay = fminf(fmaxf(qy - fy, 0.0f), 1.0f);
    const float ax = fminf(fmaxf(qx - fx, 0.0f), 1.0f);
    const int iy = (int)fy;
    const int ix = (int)fx;

    const f4* __restrict__ img4 = (const f4*)image;
    // float4-unit index of (b, iy, ix, 4q); (p & ~0xFFFF) == b*H*W.
    // Max value < 2^27: pure 32-bit arithmetic.
    const int base = ((p & ~0xFFFF) + (iy << 8) + ix) * QUADS + q;

    const f4 tl = img4[base];
    const f4 tr = img4[base + QUADS];
    const f4 bl = img4[base + R];
    const f4 br = img4[base + R + QUADS];

    f4 r;
    #pragma unroll
    for (int e = 0; e < 4; ++e) {
        const float top = fmaf(ax, tr[e] - tl[e], tl[e]);
        const float bot = fmaf(ax, br[e] - bl[e], bl[e]);
        r[e] = fmaf(ay, bot - top, top);
    }

    ((f4*)out)[gid] = r;
}

extern "C" void kernel_launch(void* const* d_in, const int* in_sizes, int n_in,
                              void* d_out, int out_size, void* d_ws, size_t ws_size,
                              hipStream_t stream) {
    const float* image = (const float*)d_in[0];
    const float* flow  = (const float*)d_in[1];
    float* out = (float*)d_out;

    constexpr int B = 8, H = 256, W = 256, C = 64;
    const int total_threads = B * H * W * (C / 4);  // 8,388,608
    const int block = 256;
    const int grid = total_threads / block;         // 32,768

    warp_bilinear_kernel<<<grid, block, 0, stream>>>(image, flow, out);
}